// Round 15
// baseline (86.892 us; speedup 1.0000x reference)
//
#include <hip/hip_runtime.h>
#include <hip/hip_bf16.h>
#include <math.h>

// TMM: T[f][lam], 16-step complex recurrence on a 2-component row vector.
// Round 12/14: latency test. ALL per-step tables preloaded to registers
// (96 VGPR) before a pure-register compute phase; zero memory ops inside
// the recurrence. VOP3P asm complex math, poly exp2, FPB=4.
// (r14: fix float4 .xy/.zw swizzle -> explicit v2 construction)

#define ST 1024          // padded lam stride for tables
#define FPB 4            // f values per thread

typedef float v2 __attribute__((ext_vector_type(2)));

// z = a *c b  (complex):  z = [ar*br - ai*bi, ar*bi + ai*br]
static __device__ __forceinline__ v2 cmul_pk(v2 a, v2 b) {
    v2 t, z;
    asm("v_pk_mul_f32 %0, %1, %2 op_sel:[0,0] op_sel_hi:[0,1]"
        : "=v"(t) : "v"(a), "v"(b));
    asm("v_pk_fma_f32 %0, %1, %2, %3 op_sel:[1,1,0] op_sel_hi:[1,0,1] neg_lo:[1,0,0] neg_hi:[0,0,0]"
        : "=v"(z) : "v"(a), "v"(b), "v"(t));
    return z;
}

// z = a *c b + c  (complex fma)
static __device__ __forceinline__ v2 cfma_pk(v2 a, v2 b, v2 c) {
    v2 t, z;
    asm("v_pk_fma_f32 %0, %1, %2, %3 op_sel:[0,0,0] op_sel_hi:[0,1,1]"
        : "=v"(t) : "v"(a), "v"(b), "v"(c));
    asm("v_pk_fma_f32 %0, %1, %2, %3 op_sel:[1,1,0] op_sel_hi:[1,0,1] neg_lo:[1,0,0] neg_hi:[0,0,0]"
        : "=v"(z) : "v"(a), "v"(b), "v"(t));
    return z;
}

// pp = broadcast(d, half P) * K   (packed mul with op_sel broadcast)
template <int P>
static __device__ __forceinline__ v2 pk_mul_bc(v2 d, v2 K) {
    v2 r;
    if constexpr (P == 0) {
        asm("v_pk_mul_f32 %0, %1, %2 op_sel:[0,0] op_sel_hi:[0,1]"
            : "=v"(r) : "v"(d), "v"(K));
    } else {
        asm("v_pk_mul_f32 %0, %1, %2 op_sel:[1,0] op_sel_hi:[1,1]"
            : "=v"(r) : "v"(d), "v"(K));
    }
    return r;
}

// 2^x on [-0.70, 0]: deg-4 Taylor at m=-0.35 (rel err ~7e-6), 1 add + 4 fma.
static __device__ __forceinline__ float exp2_small(float x) {
    const float c0 = 0.78458455f;
    const float c1 = 0.54383054f;
    const float c2 = 0.18847589f;
    const float c3 = 0.04354510f;
    const float c4 = 0.00754577f;
    float t = x + 0.35f;
    float p = __builtin_fmaf(t, c4, c3);
    p = __builtin_fmaf(t, p, c2);
    p = __builtin_fmaf(t, p, c1);
    p = __builtin_fmaf(t, p, c0);
    return p;
}

__global__ __launch_bounds__(256) void tmm_pre(
        const float* __restrict__ lam_vac,
        const float* __restrict__ n_real,
        const float* __restrict__ n_imag,
        float2* __restrict__ kp,    // [NI][ST]: (krr, kie)
        float4* __restrict__ tq,    // [NI][ST]: (t_r, t_i, q_r, q_i)
        float* __restrict__ fin,    // [5][ST]: it0r,it0i,r0tr,r0ti,rr
        int num_lam, int NL) {
    int tid = blockIdx.x * blockDim.x + threadIdx.x;
    int ne = num_lam * (NL - 2);
    if (tid < ne) {
        int j = tid % num_lam;
        int s = tid / num_lam;
        float lam = lam_vac[j];
        const float* nr = n_real + (size_t)j * NL;
        const float* ni = n_imag + (size_t)j * NL;
        float nlr = nr[s + 1], nli = ni[s + 1];
        float nhr = nr[s + 2], nhi = ni[s + 2];
        // sin/cos arg in REVOLUTIONS: 2*delta_r/(2pi) = 2*d*n_r/lam
        // exp2 arg: -2*delta_i*log2(e) = -(4*pi*log2e)*d*n_i/lam
        kp[s * ST + j] = make_float2(2.0f * nlr / lam,
                                     -18.129440567308824f * nli / lam);
        float ur = 2.f * nlr, ui = 2.f * nli;
        float den = 1.f / (ur * ur + ui * ui);
        float sr = nlr + nhr, si = nli + nhi;   // inv_t = (nl+nh)/(2 nl)
        float dr = nlr - nhr, di = nli - nhi;   // r/t  = (nl-nh)/(2 nl)
        tq[s * ST + j] = make_float4((sr * ur + si * ui) * den,
                                     (si * ur - sr * ui) * den,
                                     (dr * ur + di * ui) * den,
                                     (di * ur - dr * ui) * den);
    } else if (tid - ne < num_lam) {
        int j = tid - ne;
        const float* nr = n_real + (size_t)j * NL;
        const float* ni = n_imag + (size_t)j * NL;
        float n0r = nr[0], n0i = ni[0];
        float n1r = nr[1], n1i = ni[1];
        float ur = 2.f * n0r, ui = 2.f * n0i;
        float den = 1.f / (ur * ur + ui * ui);
        float sr = n0r + n1r, si = n0i + n1i;
        float dr = n0r - n1r, di = n0i - n1i;
        fin[0 * ST + j] = (sr * ur + si * ui) * den;   // 1/t0 re
        fin[1 * ST + j] = (si * ur - sr * ui) * den;   // 1/t0 im
        fin[2 * ST + j] = (dr * ur + di * ui) * den;   // r0/t0 re
        fin[3 * ST + j] = (di * ur - dr * ui) * den;   // r0/t0 im
        float nLr = nr[NL - 1], nLi = ni[NL - 1];
        float d0 = 1.f / (n0r * n0r + n0i * n0i);
        fin[4 * ST + j] = (nLr * n0r + nLi * n0i) * d0; // Re(n_L/n_0)
    }
}

// One recurrence step for one f value. P = which half of dpair holds d.
template <int P>
static __device__ __forceinline__ void step_pk(
        v2 dpair, v2 K, v2 T1, v2 Q1, v2& A, v2& B, float& sdi) {
    v2 pp = pk_mul_bc<P>(dpair, K);          // (ph, pe)
    sdi += pp.y;
    float ev = exp2_small(pp.y);             // e^{-2 delta_i}, poly (no trans)
    float sn = __builtin_amdgcn_sinf(pp.x);
    float cs = __builtin_amdgcn_cosf(pp.x);
    v2 e2; e2.x = ev * cs; e2.y = ev * sn;   // exp(2i delta)
    v2 h  = cmul_pk(B, e2);                  // B * e2
    v2 n0 = cfma_pk(h, Q1, cmul_pk(A, T1)); // A*t + h*q
    v2 n1 = cfma_pk(h, T1, cmul_pk(A, Q1)); // A*q + h*t
    A = n0; B = n1;
}

// Specialized: num_inner == 16. ALL tables preloaded to registers, then a
// pure-register fully-unrolled compute phase (no memory ops in recurrence).
__global__ __launch_bounds__(256) void tmm_main16(
        const float* __restrict__ d_arr,
        const float2* __restrict__ kp,
        const float4* __restrict__ tq,
        const float* __restrict__ fin,
        float* __restrict__ out,
        int num_lam) {
    int lam = blockIdx.x * blockDim.x + threadIdx.x;
    if (lam >= num_lam) return;
    int f0 = blockIdx.y * FPB;

    // ---- Phase A: issue ALL loads (tables, d, final params) up front ----
    v2 Kreg[16];
    v2 Treg[16], Qreg[16];
#pragma unroll
    for (int s = 0; s < 16; ++s) {
        float2 kv = kp[s * ST + lam];
        Kreg[s].x = kv.x; Kreg[s].y = kv.y;
        float4 tv = tq[s * ST + lam];
        Treg[s].x = tv.x; Treg[s].y = tv.y;
        Qreg[s].x = tv.z; Qreg[s].y = tv.w;
    }

    v2 dreg[FPB][8];
#pragma unroll
    for (int fi = 0; fi < FPB; ++fi) {
        const float4* dp = reinterpret_cast<const float4*>(
            d_arr + (size_t)(f0 + fi) * 16);
#pragma unroll
        for (int k = 0; k < 4; ++k) {
            float4 v = dp[k];
            dreg[fi][2 * k + 0].x = v.x; dreg[fi][2 * k + 0].y = v.y;
            dreg[fi][2 * k + 1].x = v.z; dreg[fi][2 * k + 1].y = v.w;
        }
    }

    float t0r = fin[0 * ST + lam], t0i = fin[1 * ST + lam];
    float q0r = fin[2 * ST + lam], q0i = fin[3 * ST + lam];
    float rrv = fin[4 * ST + lam];

    // ---- Phase B: pure-register recurrence ----
    v2 v0[FPB], v1[FPB];
    float sdi[FPB];
#pragma unroll
    for (int fi = 0; fi < FPB; ++fi) {
        v0[fi].x = t0r; v0[fi].y = t0i;
        v1[fi].x = q0r; v1[fi].y = q0i;
        sdi[fi] = 0.f;
    }

#pragma unroll
    for (int sp = 0; sp < 8; ++sp) {
        // even step s = 2*sp (d in low half), odd step (high half)
#pragma unroll
        for (int fi = 0; fi < FPB; ++fi)
            step_pk<0>(dreg[fi][sp], Kreg[2 * sp], Treg[2 * sp],
                       Qreg[2 * sp], v0[fi], v1[fi], sdi[fi]);
#pragma unroll
        for (int fi = 0; fi < FPB; ++fi)
            step_pk<1>(dreg[fi][sp], Kreg[2 * sp + 1], Treg[2 * sp + 1],
                       Qreg[2 * sp + 1], v0[fi], v1[fi], sdi[fi]);
    }

#pragma unroll
    for (int fi = 0; fi < FPB; ++fi) {
        float Mr = v0[fi].x, Mi = v0[fi].y;
        out[(size_t)(f0 + fi) * num_lam + lam] =
            rrv * __builtin_amdgcn_exp2f(sdi[fi]) *
            __builtin_amdgcn_rcpf(Mr * Mr + Mi * Mi);
    }
}

// Generic scalar fallback for num_inner != 16.
__global__ __launch_bounds__(256) void tmm_main_gen(
        const float* __restrict__ d_arr,
        const float2* __restrict__ kp,
        const float4* __restrict__ tq,
        const float* __restrict__ fin,
        float* __restrict__ out,
        int num_lam, int num_inner) {
    int lam = blockIdx.x * blockDim.x + threadIdx.x;
    if (lam >= num_lam) return;
    int f0 = blockIdx.y * FPB;

    float t0r = fin[0 * ST + lam], t0i = fin[1 * ST + lam];
    float q0r = fin[2 * ST + lam], q0i = fin[3 * ST + lam];
    float rrv = fin[4 * ST + lam];

    float v0r[FPB], v0i[FPB], v1r[FPB], v1i[FPB], sdi[FPB];
#pragma unroll
    for (int fi = 0; fi < FPB; ++fi) {
        v0r[fi] = t0r; v0i[fi] = t0i;
        v1r[fi] = q0r; v1i[fi] = q0i;
        sdi[fi] = 0.f;
    }

    for (int s = 0; s < num_inner; ++s) {
        float2 kv = kp[s * ST + lam];
        float4 t4 = tq[s * ST + lam];
#pragma unroll
        for (int fi = 0; fi < FPB; ++fi) {
            float dv = d_arr[(size_t)(f0 + fi) * num_inner + s];
            float ph = dv * kv.x;
            float pe = dv * kv.y;
            sdi[fi] += pe;
            float ev = __builtin_amdgcn_exp2f(pe);
            float sn = __builtin_amdgcn_sinf(ph);
            float cs = __builtin_amdgcn_cosf(ph);
            float e2r = ev * cs, e2i = ev * sn;
            float hr = v1r[fi] * e2r - v1i[fi] * e2i;
            float hi = v1r[fi] * e2i + v1i[fi] * e2r;
            float A_r = v0r[fi], A_i = v0i[fi];
            v0r[fi] = A_r * t4.x - A_i * t4.y + hr * t4.z - hi * t4.w;
            v0i[fi] = A_r * t4.y + A_i * t4.x + hr * t4.w + hi * t4.z;
            v1r[fi] = A_r * t4.z - A_i * t4.w + hr * t4.x - hi * t4.y;
            v1i[fi] = A_r * t4.w + A_i * t4.z + hr * t4.y + hi * t4.x;
        }
    }

#pragma unroll
    for (int fi = 0; fi < FPB; ++fi) {
        float Mr = v0r[fi], Mi = v0i[fi];
        out[(size_t)(f0 + fi) * num_lam + lam] =
            rrv * __builtin_amdgcn_exp2f(sdi[fi]) *
            __builtin_amdgcn_rcpf(Mr * Mr + Mi * Mi);
    }
}

extern "C" void kernel_launch(void* const* d_in, const int* in_sizes, int n_in,
                              void* d_out, int out_size, void* d_ws, size_t ws_size,
                              hipStream_t stream) {
    const float* d_arr   = (const float*)d_in[0];
    const float* lam_vac = (const float*)d_in[1];
    const float* n_real  = (const float*)d_in[2];
    const float* n_imag  = (const float*)d_in[3];
    float* out = (float*)d_out;

    int num_lam   = in_sizes[1];
    int NL        = in_sizes[2] / num_lam;     // 18
    int num_inner = NL - 2;                    // 16
    int num_f     = in_sizes[0] / num_inner;   // 2048

    // workspace: kp [NI][ST] float2 | tq [NI][ST] float4 | fin [5][ST]
    char* ws = (char*)d_ws;
    float2* kp  = (float2*)ws;
    float4* tq  = (float4*)(ws + (size_t)num_inner * ST * sizeof(float2));
    float*  fin = (float*)(ws + (size_t)num_inner * ST * (sizeof(float2) + sizeof(float4)));

    int pre_threads = num_lam * (num_inner + 1);
    dim3 preGrid((pre_threads + 255) / 256);
    tmm_pre<<<preGrid, 256, 0, stream>>>(lam_vac, n_real, n_imag,
                                         kp, tq, fin, num_lam, NL);

    dim3 grid((num_lam + 255) / 256, num_f / FPB);
    if (num_inner == 16) {
        tmm_main16<<<grid, 256, 0, stream>>>(d_arr, kp, tq, fin, out, num_lam);
    } else {
        tmm_main_gen<<<grid, 256, 0, stream>>>(d_arr, kp, tq, fin, out,
                                               num_lam, num_inner);
    }
}